// Round 25
// baseline (24.492 us; speedup 1.0000x reference)
//
#include <hip/hip_runtime.h>
#include <hip/hip_bf16.h>

typedef __attribute__((ext_vector_type(8))) short bf16x8;
typedef __attribute__((ext_vector_type(4))) float f32x4;

#define NPIX 32768

__device__ __forceinline__ ushort f2bf(float f) {
    __hip_bfloat16 h = __float2bfloat16(f);   // single v_cvt, RNE
    ushort u; __builtin_memcpy(&u, &h, 2);
    return u;
}

// R21 + COALESCED weight repack: the old repack read W1/W2 with 32+9
// scattered 4B loads per thread (every lane a distinct 256B-strided cache
// line -- the worst-case pattern whose removal in GEMM gave the R15 win).
// Now: coalesced float4 global reads (thread's d-quad dq=t&15 is constant
// -> 4 BN scales computed once), scatter moved to the LDS-WRITE side
// (2B ds_writes; LDS absorbs scatter at ~69 TB/s). Cuts the per-block
// startup ramp that sits serially before the barrier on every CU.
// Geometry identical to R21: block = 2 rows / 128 px, 512 threads, 8 waves,
// wave = (row-half, col-quarter) 16 px end-to-end; zero barriers after the
// single weight/staging barrier.
// LDS: 8 arenas x 10240 @0 | w1s 32768 @81920 | w2s 18432 @114688
//   => 133120 B, 1 block/CU (8 waves/CU).
// Arena phases: xs bf16 [16][512B] @0 swz | hs bf16 [16][128B] @8192 swz |
//   ks f32 [16][148] @0 (aliases xs+hs; safe per-wave in-order LDS).
// XCD k owns image k for halo L2 locality.
__global__ __launch_bounds__(512, 1) void fused_kernel(
        const float* __restrict__ x,
        const float* __restrict__ W1, const float* __restrict__ b1,
        const float* __restrict__ gamma, const float* __restrict__ beta,
        const float* __restrict__ mean, const float* __restrict__ var,
        const float* __restrict__ W2, const float* __restrict__ b2,
        float* __restrict__ ker, float* __restrict__ out) {
    __shared__ __align__(16) char smem[133120];
    const int t = threadIdx.x;
    const int wv = t >> 6, ln = t & 63;
    char* arena = smem + wv * 10240;
    char* w1s   = smem + 81920;                  // block-shared packed W1
    char* w2s   = smem + 114688;                 // block-shared packed W2
    const int bid = (int)blockIdx.x;
    const int img = bid & 7;                     // XCD k <- image k
    const int rp  = bid >> 3;                    // row pair 0..31
    const int i   = rp * 2 + (wv >> 2);          // image row of this wave
    const int lb  = img * 64 + i;                // b*64 + i
    const int j0  = (wv & 3) * 16;               // wave's first column
    const int pw  = lb * 64 + j0;                // wave's first pixel
    const int r16 = ln & 15, g = ln >> 4;

    // ---- repack W1 -> w1s: COALESCED f32x4 reads, scattered 2B LDS writes ----
    // Thread's d-quad is constant: dq = t&15 -> d = dq*4+j; 4 scales once.
    {
        const int dq = t & 15;
        const int dtq = dq >> 2;                  // dt, constant per thread
        const int rbase = (dq & 3) * 4;           // r = rbase + j
        float sc4[4];
        #pragma unroll
        for (int j = 0; j < 4; j++) {
            int d = dq * 4 + j;
            sc4[j] = gamma[d] * rsqrtf(var[d] + 1e-3f);
        }
        const float4* w1v = (const float4*)W1;    // [c][dq]: f = c*16 + dq
        ushort* w1u = (ushort*)w1s;
        #pragma unroll
        for (int m = 0; m < 8; m++) {
            int f = m * 512 + t;                  // 4096 float4 chunks
            int c = f >> 4;
            int kk = c >> 5, c3 = (c >> 3) & 3, cc = c & 7;
            float4 v = w1v[f];
            int base = ((((kk * 4 + dtq) << 6) + (c3 << 4) + rbase) << 3) + cc;
            w1u[base]      = f2bf(v.x * sc4[0]);
            w1u[base + 8]  = f2bf(v.y * sc4[1]);
            w1u[base + 16] = f2bf(v.z * sc4[2]);
            w1u[base + 24] = f2bf(v.w * sc4[3]);
        }
    }
    // ---- repack W2 -> w2s: coalesced f32x4 reads, scattered LDS writes ----
    {
        const float4* w2v = (const float4*)W2;    // 2304 float4 (rows of 36)
        ushort* w2u = (ushort*)w2s;
        #pragma unroll
        for (int m = 0; m < 5; m++) {
            int f = m * 512 + t;
            if (f < 2304) {
                int dcol = f / 36, eq = f - dcol * 36;
                int kk = dcol >> 5, c3 = (dcol >> 3) & 3, cc = dcol & 7;
                float4 v = w2v[f];
                float va[4]; *(float4*)va = v;
                #pragma unroll
                for (int j = 0; j < 4; j++) {
                    int e = eq * 4 + j;
                    int et = e >> 4, r = e & 15;
                    w2u[((((kk * 9 + et) << 6) + (c3 << 4) + r) << 3) + cc] = f2bf(va[j]);
                }
            }
        }
    }
    // ---- per-thread BN-folded bias (L1-hot 256B arrays) ----
    float b1fv[4];
    #pragma unroll
    for (int dt = 0; dt < 4; dt++) {
        int d = dt * 16 + r16;
        float sc = gamma[d] * rsqrtf(var[d] + 1e-3f);
        b1fv[dt] = (b1[d] - mean[d]) * sc + beta[d];
    }

    // ---- stage wave's 16 x-rows: f32 -> bf16, XOR-swizzled, local rows ----
    {
        const float4* xg = (const float4*)(x + (size_t)pw * 256);
        #pragma unroll
        for (int it = 0; it < 16; it++) {
            float4 v = xg[it * 64 + ln];
            ushort4 b4; b4.x = f2bf(v.x); b4.y = f2bf(v.y);
            b4.z = f2bf(v.z); b4.w = f2bf(v.w);
            int bcol = (ln * 8) ^ ((it & 7) << 4);
            *(ushort4*)(arena + it * 512 + bcol) = b4;
        }
    }
    __syncthreads();   // w1s/w2s visible to all waves (x staging wave-private)

    // ---- GEMM1: 16 px x 64 d; A from arena xs, B from w1s (LDS) ----
    f32x4 acc[4];
    #pragma unroll
    for (int dt = 0; dt < 4; dt++) {
        float bv = b1fv[dt];
        acc[dt] = (f32x4){bv, bv, bv, bv};
    }
    #pragma unroll
    for (int kk = 0; kk < 8; kk++) {
        int bcA = (kk * 64 + g * 16) ^ ((r16 & 7) << 4);
        bf16x8 av = *(const bf16x8*)(arena + r16 * 512 + bcA);
        #pragma unroll
        for (int dt = 0; dt < 4; dt++) {
            bf16x8 bv = *(const bf16x8*)(w1s + (((kk * 4 + dt) << 6) + ln) * 16);
            acc[dt] = __builtin_amdgcn_mfma_f32_16x16x32_bf16(av, bv, acc[dt], 0, 0, 0);
        }
    }

    // relu -> bf16 -> hs (arena+8192, local rows 0..15, swizzled)
    #pragma unroll
    for (int dt = 0; dt < 4; dt++) {
        #pragma unroll
        for (int r = 0; r < 4; r++) {
            int q = g * 4 + r;                        // local px (C/D row)
            int bcol = ((dt * 16 + r16) * 2) ^ ((q & 7) << 4);
            *(ushort*)(arena + 8192 + q * 128 + bcol) = f2bf(fmaxf(acc[dt][r], 0.f));
        }
    }

    // ---- invol window preload: latency hides under GEMM2 ----
    const f32x4* xv4 = (const f32x4*)x;
    const f32x4 z4 = {0.f, 0.f, 0.f, 0.f};
    f32x4 wa[3], wb[3], wc[3], wd[3];   // cols j-1, j, j+1, j+2
    #pragma unroll
    for (int r = 0; r < 3; r++) {
        int row = i + r - 1;
        bool rv = (unsigned)row < 64u;
        const size_t rb = (size_t)(lb + r - 1) * 64;
        wa[r] = (rv && j0 > 0) ? xv4[(rb + (j0 - 1)) * 64 + ln] : z4;
        wb[r] = rv ? xv4[(rb + j0) * 64 + ln] : z4;
        wc[r] = rv ? xv4[(rb + j0 + 1) * 64 + ln] : z4;   // j0+1 <= 49 < 64
        wd[r] = rv ? xv4[(rb + j0 + 2) * 64 + ln] : z4;   // j0+2 <= 50 < 64
    }

    // ---- GEMM2: 16 px x 144 e; A from hs, B from w2s (LDS) ----
    f32x4 acc2[9];
    #pragma unroll
    for (int et = 0; et < 9; et++) {
        float bv = b2[et * 16 + r16];
        acc2[et] = (f32x4){bv, bv, bv, bv};
    }
    #pragma unroll
    for (int kk = 0; kk < 2; kk++) {
        int bcA = (kk * 64 + g * 16) ^ ((r16 & 7) << 4);
        bf16x8 av = *(const bf16x8*)(arena + 8192 + r16 * 128 + bcA);
        #pragma unroll
        for (int et = 0; et < 9; et++) {
            bf16x8 bv = *(const bf16x8*)(w2s + (((kk * 9 + et) << 6) + ln) * 16);
            acc2[et] = __builtin_amdgcn_mfma_f32_16x16x32_bf16(av, bv, acc2[et], 0, 0, 0);
        }
    }

    // ---- ks: f32 transpose into wave arena (LDS only); acc2 dies here ----
    float* ksf = (float*)arena;                       // [16][148]
    #pragma unroll
    for (int et = 0; et < 9; et++) {
        #pragma unroll
        for (int r = 0; r < 4; r++) {
            int q = g * 4 + r;
            ksf[q * 148 + et * 16 + r16] = acc2[et][r];
        }
    }

    // ---- involution: 4-column shift window, prefetch depth 2 ----
    const int s4 = (ln & 3) * 4;
    #pragma unroll 4
    for (int pp = 0; pp < 16; pp++) {
        const int j = j0 + pp;
        const float* kp = ksf + pp * 148 + s4;
        f32x4 o = {0.f, 0.f, 0.f, 0.f};
        #pragma unroll
        for (int r = 0; r < 3; r++) {
            o += (*(const f32x4*)(kp + (r * 3 + 0) * 16)) * wa[r];
            o += (*(const f32x4*)(kp + (r * 3 + 1) * 16)) * wb[r];
            o += (*(const f32x4*)(kp + (r * 3 + 2) * 16)) * wc[r];
        }
        __builtin_nontemporal_store(o, &((f32x4*)out)[(size_t)(lb * 64 + j) * 64 + ln]);
        #pragma unroll
        for (int r = 0; r < 3; r++) { wa[r] = wb[r]; wb[r] = wc[r]; wc[r] = wd[r]; }
        if (pp < 14) {
            const int jn = j + 3;                      // consumed at pp+2
            const bool cv = jn < 64;
            #pragma unroll
            for (int r = 0; r < 3; r++) {
                int row = i + r - 1;
                bool rv = (unsigned)row < 64u;
                wd[r] = (rv && cv)
                    ? xv4[((size_t)(lb + r - 1) * 64 + jn) * 64 + ln] : z4;
            }
        }
    }

    // ---- coalesced ker epilogue: ksf -> 9 x 1KB contiguous NT stores ----
    {
        float* kerW = ker + (size_t)pw * 144;   // wave's 2304 floats
        #pragma unroll
        for (int m = 0; m < 9; m++) {
            int fidx = m * 64 + ln;          // f32x4 index within wave region
            int row  = fidx / 36;            // px row 0..15
            int col4 = fidx - row * 36;      // f32x4 within row (144/4=36)
            f32x4 v = *(const f32x4*)(ksf + row * 148 + col4 * 4);
            __builtin_nontemporal_store(v, (f32x4*)(kerW + fidx * 4));
        }
    }
}

extern "C" void kernel_launch(void* const* d_in, const int* in_sizes, int n_in,
                              void* d_out, int out_size, void* d_ws, size_t ws_size,
                              hipStream_t stream) {
    const float* x     = (const float*)d_in[0];
    const float* W1    = (const float*)d_in[1];
    const float* b1    = (const float*)d_in[2];
    const float* gamma = (const float*)d_in[3];
    const float* beta  = (const float*)d_in[4];
    const float* mmean = (const float*)d_in[5];
    const float* mvar  = (const float*)d_in[6];
    const float* W2    = (const float*)d_in[7];
    const float* b2    = (const float*)d_in[8];

    float* out_main = (float*)d_out;                 // (B,H,W,C)   = 8388608 f32
    float* out_ker  = (float*)d_out + 8388608;       // (B,H,W,144) = 4718592 f32

    fused_kernel<<<NPIX / 128, 512, 0, stream>>>(
        x, W1, b1, gamma, beta, mmean, mvar, W2, b2, out_ker, out_main);
}

// Round 26
// 21.187 us; speedup vs baseline: 1.1560x; 1.1560x over previous
//
#include <hip/hip_runtime.h>
#include <hip/hip_bf16.h>

typedef __attribute__((ext_vector_type(8))) short bf16x8;
typedef __attribute__((ext_vector_type(4))) float f32x4;

#define NPIX 32768

__device__ __forceinline__ ushort f2bf(float f) {
    __hip_bfloat16 h = __float2bfloat16(f);   // single v_cvt, RNE
    ushort u; __builtin_memcpy(&u, &h, 2);
    return u;
}

// FINAL (= R21, measured 21.18 us): single fused kernel, merged fold.
// Each block repacks W1/W2 directly from global (L2/L3-hot 100KB) into its
// own LDS copies (fragment order, BN-folded); the scattered 4B loads hide
// under the HBM-bound x staging and proved cheaper than any alternative
// (coalesced-read/scattered-LDS-write variant regressed: bank conflicts).
// Block = 2 image rows, 128 px, 512 threads (8 waves); wave = (row-half,
// col-quarter), 16 px end-to-end. Zero barriers after the single
// weight/staging barrier; everything downstream is wave-private.
// LDS: 8 arenas x 10240 @0 | w1s 32768 @81920 | w2s 18432 @114688
//   => 133120 B, 1 block/CU (8 waves/CU).
// Arena phases: xs bf16 [16][512B] @0 swz | hs bf16 [16][128B] @8192 swz |
//   ks f32 [16][148] @0 (aliases xs+hs; safe per-wave in-order LDS).
// Session ladder: 200 -> 43.7 -> 41.1 -> 37.6 -> 36.2 -> 27.7 (fragment-
// order weights) -> 26.9 (W1 in LDS) -> 26.4 (2-row block) -> 25.6 (W2 in
// LDS) -> 21.2 (merged fold). Falsified: TLP x4, store-sink x2,
// de-lockstep, repack-coalescing. Compulsory-traffic floor ~13.7 us.
__global__ __launch_bounds__(512, 1) void fused_kernel(
        const float* __restrict__ x,
        const float* __restrict__ W1, const float* __restrict__ b1,
        const float* __restrict__ gamma, const float* __restrict__ beta,
        const float* __restrict__ mean, const float* __restrict__ var,
        const float* __restrict__ W2, const float* __restrict__ b2,
        float* __restrict__ ker, float* __restrict__ out) {
    __shared__ __align__(16) char smem[133120];
    const int t = threadIdx.x;
    const int wv = t >> 6, ln = t & 63;
    char* arena = smem + wv * 10240;
    char* w1s   = smem + 81920;                  // block-shared packed W1
    char* w2s   = smem + 114688;                 // block-shared packed W2
    const int bid = (int)blockIdx.x;
    const int img = bid & 7;                     // XCD k <- image k
    const int rp  = bid >> 3;                    // row pair 0..31
    const int i   = rp * 2 + (wv >> 2);          // image row of this wave
    const int lb  = img * 64 + i;                // b*64 + i
    const int j0  = (wv & 3) * 16;               // wave's first column
    const int pw  = lb * 64 + j0;                // wave's first pixel
    const int r16 = ln & 15, g = ln >> 4;

    // ---- repack W1 -> w1s (2048 x 16B chunks, 4 per thread) ----
    #pragma unroll
    for (int m = 0; m < 4; m++) {
        int idx = m * 512 + t;
        int ln2 = idx & 63, dt = (idx >> 6) & 3, kk = idx >> 8;
        int d = dt * 16 + (ln2 & 15);
        float sc = gamma[d] * rsqrtf(var[d] + 1e-3f);
        int cbase = kk * 32 + (ln2 >> 4) * 8;
        ushort tmp[8];
        #pragma unroll
        for (int cc = 0; cc < 8; cc++)
            tmp[cc] = f2bf(W1[(cbase + cc) * 64 + d] * sc);
        __builtin_memcpy(w1s + idx * 16, tmp, 16);
    }
    // ---- repack W2 -> w2s (1152 x 16B chunks) ----
    #pragma unroll
    for (int m = 0; m < 3; m++) {
        int idx = m * 512 + t;
        if (idx < 1152) {
            int ln2 = idx & 63, rem = idx >> 6;   // rem < 18
            int et = rem % 9, kk = rem / 9;
            int e = et * 16 + (ln2 & 15);
            int dbase = kk * 32 + (ln2 >> 4) * 8;
            ushort tmp[8];
            #pragma unroll
            for (int cc = 0; cc < 8; cc++)
                tmp[cc] = f2bf(W2[(dbase + cc) * 144 + e]);
            __builtin_memcpy(w2s + idx * 16, tmp, 16);
        }
    }
    // ---- per-thread BN-folded bias (L1-hot 256B arrays) ----
    float b1fv[4];
    #pragma unroll
    for (int dt = 0; dt < 4; dt++) {
        int d = dt * 16 + r16;
        float sc = gamma[d] * rsqrtf(var[d] + 1e-3f);
        b1fv[dt] = (b1[d] - mean[d]) * sc + beta[d];
    }

    // ---- stage wave's 16 x-rows: f32 -> bf16, XOR-swizzled, local rows ----
    {
        const float4* xg = (const float4*)(x + (size_t)pw * 256);
        #pragma unroll
        for (int it = 0; it < 16; it++) {
            float4 v = xg[it * 64 + ln];
            ushort4 b4; b4.x = f2bf(v.x); b4.y = f2bf(v.y);
            b4.z = f2bf(v.z); b4.w = f2bf(v.w);
            int bcol = (ln * 8) ^ ((it & 7) << 4);
            *(ushort4*)(arena + it * 512 + bcol) = b4;
        }
    }
    __syncthreads();   // w1s/w2s visible to all waves (x staging wave-private)

    // ---- GEMM1: 16 px x 64 d; A from arena xs, B from w1s (LDS) ----
    f32x4 acc[4];
    #pragma unroll
    for (int dt = 0; dt < 4; dt++) {
        float bv = b1fv[dt];
        acc[dt] = (f32x4){bv, bv, bv, bv};
    }
    #pragma unroll
    for (int kk = 0; kk < 8; kk++) {
        int bcA = (kk * 64 + g * 16) ^ ((r16 & 7) << 4);
        bf16x8 av = *(const bf16x8*)(arena + r16 * 512 + bcA);
        #pragma unroll
        for (int dt = 0; dt < 4; dt++) {
            bf16x8 bv = *(const bf16x8*)(w1s + (((kk * 4 + dt) << 6) + ln) * 16);
            acc[dt] = __builtin_amdgcn_mfma_f32_16x16x32_bf16(av, bv, acc[dt], 0, 0, 0);
        }
    }

    // relu -> bf16 -> hs (arena+8192, local rows 0..15, swizzled)
    #pragma unroll
    for (int dt = 0; dt < 4; dt++) {
        #pragma unroll
        for (int r = 0; r < 4; r++) {
            int q = g * 4 + r;                        // local px (C/D row)
            int bcol = ((dt * 16 + r16) * 2) ^ ((q & 7) << 4);
            *(ushort*)(arena + 8192 + q * 128 + bcol) = f2bf(fmaxf(acc[dt][r], 0.f));
        }
    }

    // ---- invol window preload: latency hides under GEMM2 ----
    const f32x4* xv4 = (const f32x4*)x;
    const f32x4 z4 = {0.f, 0.f, 0.f, 0.f};
    f32x4 wa[3], wb[3], wc[3], wd[3];   // cols j-1, j, j+1, j+2
    #pragma unroll
    for (int r = 0; r < 3; r++) {
        int row = i + r - 1;
        bool rv = (unsigned)row < 64u;
        const size_t rb = (size_t)(lb + r - 1) * 64;
        wa[r] = (rv && j0 > 0) ? xv4[(rb + (j0 - 1)) * 64 + ln] : z4;
        wb[r] = rv ? xv4[(rb + j0) * 64 + ln] : z4;
        wc[r] = rv ? xv4[(rb + j0 + 1) * 64 + ln] : z4;   // j0+1 <= 49 < 64
        wd[r] = rv ? xv4[(rb + j0 + 2) * 64 + ln] : z4;   // j0+2 <= 50 < 64
    }

    // ---- GEMM2: 16 px x 144 e; A from hs, B from w2s (LDS) ----
    f32x4 acc2[9];
    #pragma unroll
    for (int et = 0; et < 9; et++) {
        float bv = b2[et * 16 + r16];
        acc2[et] = (f32x4){bv, bv, bv, bv};
    }
    #pragma unroll
    for (int kk = 0; kk < 2; kk++) {
        int bcA = (kk * 64 + g * 16) ^ ((r16 & 7) << 4);
        bf16x8 av = *(const bf16x8*)(arena + 8192 + r16 * 128 + bcA);
        #pragma unroll
        for (int et = 0; et < 9; et++) {
            bf16x8 bv = *(const bf16x8*)(w2s + (((kk * 9 + et) << 6) + ln) * 16);
            acc2[et] = __builtin_amdgcn_mfma_f32_16x16x32_bf16(av, bv, acc2[et], 0, 0, 0);
        }
    }

    // ---- ks: f32 transpose into wave arena (LDS only); acc2 dies here ----
    float* ksf = (float*)arena;                       // [16][148]
    #pragma unroll
    for (int et = 0; et < 9; et++) {
        #pragma unroll
        for (int r = 0; r < 4; r++) {
            int q = g * 4 + r;
            ksf[q * 148 + et * 16 + r16] = acc2[et][r];
        }
    }

    // ---- involution: 4-column shift window, prefetch depth 2 ----
    const int s4 = (ln & 3) * 4;
    #pragma unroll 4
    for (int pp = 0; pp < 16; pp++) {
        const int j = j0 + pp;
        const float* kp = ksf + pp * 148 + s4;
        f32x4 o = {0.f, 0.f, 0.f, 0.f};
        #pragma unroll
        for (int r = 0; r < 3; r++) {
            o += (*(const f32x4*)(kp + (r * 3 + 0) * 16)) * wa[r];
            o += (*(const f32x4*)(kp + (r * 3 + 1) * 16)) * wb[r];
            o += (*(const f32x4*)(kp + (r * 3 + 2) * 16)) * wc[r];
        }
        __builtin_nontemporal_store(o, &((f32x4*)out)[(size_t)(lb * 64 + j) * 64 + ln]);
        #pragma unroll
        for (int r = 0; r < 3; r++) { wa[r] = wb[r]; wb[r] = wc[r]; wc[r] = wd[r]; }
        if (pp < 14) {
            const int jn = j + 3;                      // consumed at pp+2
            const bool cv = jn < 64;
            #pragma unroll
            for (int r = 0; r < 3; r++) {
                int row = i + r - 1;
                bool rv = (unsigned)row < 64u;
                wd[r] = (rv && cv)
                    ? xv4[((size_t)(lb + r - 1) * 64 + jn) * 64 + ln] : z4;
            }
        }
    }

    // ---- coalesced ker epilogue: ksf -> 9 x 1KB contiguous NT stores ----
    {
        float* kerW = ker + (size_t)pw * 144;   // wave's 2304 floats
        #pragma unroll
        for (int m = 0; m < 9; m++) {
            int fidx = m * 64 + ln;          // f32x4 index within wave region
            int row  = fidx / 36;            // px row 0..15
            int col4 = fidx - row * 36;      // f32x4 within row (144/4=36)
            f32x4 v = *(const f32x4*)(ksf + row * 148 + col4 * 4);
            __builtin_nontemporal_store(v, (f32x4*)(kerW + fidx * 4));
        }
    }
}

extern "C" void kernel_launch(void* const* d_in, const int* in_sizes, int n_in,
                              void* d_out, int out_size, void* d_ws, size_t ws_size,
                              hipStream_t stream) {
    const float* x     = (const float*)d_in[0];
    const float* W1    = (const float*)d_in[1];
    const float* b1    = (const float*)d_in[2];
    const float* gamma = (const float*)d_in[3];
    const float* beta  = (const float*)d_in[4];
    const float* mmean = (const float*)d_in[5];
    const float* mvar  = (const float*)d_in[6];
    const float* W2    = (const float*)d_in[7];
    const float* b2    = (const float*)d_in[8];

    float* out_main = (float*)d_out;                 // (B,H,W,C)   = 8388608 f32
    float* out_ker  = (float*)d_out + 8388608;       // (B,H,W,144) = 4718592 f32

    fused_kernel<<<NPIX / 128, 512, 0, stream>>>(
        x, W1, b1, gamma, beta, mmean, mvar, W2, b2, out_ker, out_main);
}